// Round 8
// baseline (517.817 us; speedup 1.0000x reference)
//
#include <hip/hip_runtime.h>
#include <hip/hip_bf16.h>
#include <math.h>

namespace {

constexpr int B_ = 2, P_ = 12, N_ = 170, DM_ = 64, H_ = 8, DK_ = 8, DH_ = 32, DF_ = 256;
constexpr int T_ = B_ * P_ * N_;        // 4080 tokens
constexpr float SQRT_DK = 2.8284271247461903f;

constexpr int NG_ = 12;                 // 192 output cols / 16
constexpr int NC_ = 66;                 // 2112 K / 32
constexpr int WFRAG_G = NG_ * NC_ * 64 * 8;   // shorts per graph = 405504

typedef __attribute__((ext_vector_type(4))) short short4v;
typedef __attribute__((ext_vector_type(8))) short short8v;
typedef __attribute__((ext_vector_type(4))) float float4v;

// float -> bf16 bits, round-to-nearest-even
__device__ __forceinline__ unsigned short f2bf(float x) {
    union { float f; unsigned int u; } c; c.f = x;
    unsigned int r = (c.u + 0x7FFFu + ((c.u >> 16) & 1u)) >> 16;
    return (unsigned short)r;
}

// ---------- meta hidden (x3 batched): hr = relu(c_x @ w1 + b1)  [T_,32] ----------
__global__ void k_hr3(const float* __restrict__ c_x,
                      const float* __restrict__ w1a, const float* __restrict__ b1a,
                      const float* __restrict__ w1b, const float* __restrict__ b1b,
                      const float* __restrict__ w1c, const float* __restrict__ b1c,
                      float* __restrict__ hra, float* __restrict__ hrb,
                      float* __restrict__ hrc) {
    int z = blockIdx.y;
    const float* w1 = z == 0 ? w1a : (z == 1 ? w1b : w1c);
    const float* b1 = z == 0 ? b1a : (z == 1 ? b1b : b1c);
    float* hr = z == 0 ? hra : (z == 1 ? hrb : hrc);
    int idx = blockIdx.x * 256 + threadIdx.x;          // t*32 + j
    if (idx >= T_ * DH_) return;
    int t = idx / DH_, j = idx % DH_;
    float acc = b1[j];
    const float* cx = c_x + t * DM_;
    #pragma unroll
    for (int d = 0; d < DM_; ++d) acc += cx[d] * w1[d * DH_ + j];
    hr[idx] = fmaxf(acc, 0.f);
}

// ---------- one-time w2/b2 -> bf16 B-fragment-linear permute ----------
__global__ void k_wconv(const float* __restrict__ w2a, const float* __restrict__ b2a,
                        const float* __restrict__ w2b, const float* __restrict__ b2b,
                        const float* __restrict__ w2c, const float* __restrict__ b2c,
                        unsigned short* __restrict__ Wfrag) {
    int idx = blockIdx.x * 256 + threadIdx.x;   // ((g*12+ng)*66+c)*64 + lane
    if (idx >= 3 * NG_ * NC_ * 64) return;
    int lane = idx & 63;
    int c = (idx >> 6) % NC_;
    int ng = (idx >> 6) / NC_ % NG_;
    int g = idx / (64 * NC_ * NG_);
    const float* w2 = g == 0 ? w2a : (g == 1 ? w2b : w2c);
    const float* b2 = g == 0 ? b2a : (g == 1 ? b2b : b2c);
    int m = ng * 16 + (lane & 15);
    int u = c >> 1;                              // jh
    int d0 = (c & 1) * 32 + (lane >> 4) * 8;
    const float* src = (u < DH_) ? (w2 + u * 12288 + m * 64 + d0) : (b2 + m * 64 + d0);
    short8v o;
    #pragma unroll
    for (int j = 0; j < 8; ++j) o[j] = (short)f2bf(src[j]);
    *(short8v*)(Wfrag + (size_t)idx * 8) = o;
}

// ---------- meta+mhlin GEMM v2: no LDS, no barriers ----------
__global__ __launch_bounds__(256) void k_meta_gemm2(
    const float* __restrict__ hr0, const float* __restrict__ hr1,
    const float* __restrict__ xin,
    const unsigned short* __restrict__ Wf0, const unsigned short* __restrict__ Wf1,
    float* __restrict__ out0, float* __restrict__ out1) {
    const int bz = blockIdx.z;
    const float* hr = bz ? hr1 : hr0;
    const unsigned short* Wf = bz ? Wf1 : Wf0;
    float* out = bz ? out1 : out0;

    const int tid = threadIdx.x;
    const int wv = tid >> 6, lane = tid & 63;
    const int l15 = lane & 15, quad = lane >> 4;
    const int g16 = blockIdx.x * 4 + wv;
    if (g16 >= 255) return;
    const int t = g16 * 16 + l15;
    const int nb = blockIdx.y;                   // 0..2

    const float* xp = xin + t * 64 + quad * 8;
    float4v xa = *(const float4v*)(xp);
    float4v xb = *(const float4v*)(xp + 4);
    float4v xc = *(const float4v*)(xp + 32);
    float4v xd = *(const float4v*)(xp + 36);
    float xr[16] = {xa.x, xa.y, xa.z, xa.w, xb.x, xb.y, xb.z, xb.w,
                    xc.x, xc.y, xc.z, xc.w, xd.x, xd.y, xd.z, xd.w};

    const float* hrp = hr + t * 32;
    float4v acc[4] = {{0.f,0.f,0.f,0.f},{0.f,0.f,0.f,0.f},
                      {0.f,0.f,0.f,0.f},{0.f,0.f,0.f,0.f}};

    const unsigned short* wb = Wf + ((size_t)(nb * 4) * NC_ * 64 + lane) * 8;
    const size_t qstride = (size_t)NC_ * 64 * 8;
    const size_t cstride = 64 * 8;

    for (int u = 0; u < 33; ++u) {
        float hrv = (u < DH_) ? hrp[u] : 1.0f;
        short8v a0, a1;
        #pragma unroll
        for (int j = 0; j < 8; ++j) {
            a0[j] = (short)f2bf(hrv * xr[j]);
            a1[j] = (short)f2bf(hrv * xr[8 + j]);
        }
        const unsigned short* wc = wb + (size_t)(2 * u) * cstride;
        #pragma unroll
        for (int q = 0; q < 4; ++q) {
            short8v b0 = *(const short8v*)(wc + q * qstride);
            short8v b1 = *(const short8v*)(wc + q * qstride + cstride);
            acc[q] = __builtin_amdgcn_mfma_f32_16x16x32_bf16(a0, b0, acc[q], 0, 0, 0);
            acc[q] = __builtin_amdgcn_mfma_f32_16x16x32_bf16(a1, b1, acc[q], 0, 0, 0);
        }
    }

    #pragma unroll
    for (int q = 0; q < 4; ++q) {
        #pragma unroll
        for (int r = 0; r < 4; ++r) {
            int tt = g16 * 16 + quad * 4 + r;
            out[tt * 192 + nb * 64 + q * 16 + l15] = acc[q][r];
        }
    }
}

// ---------- retnet temporal retention: block per (b,n), 256 thr ----------
__global__ __launch_bounds__(256) void k_retnet(const float* __restrict__ qkv,
                                                const float* __restrict__ Dm,
                                                float* __restrict__ att) {
    const int bn = blockIdx.x;           // b*N + n
    const int b = bn / N_, n = bn % N_;
    __shared__ float S[12][192];
    __shared__ float Ds[8 * 145];
    const int tid = threadIdx.x;
    for (int e = tid; e < 12 * 192; e += 256) {
        int p = e / 192, c = e % 192;
        S[p][c] = qkv[((size_t)((b * P_ + p) * N_ + n)) * 192 + c];
    }
    for (int e = tid; e < 1152; e += 256) {
        Ds[(e / 144) * 145 + (e % 144)] = Dm[e];
    }
    __syncthreads();
    const int qq = tid >> 6;
    const int lane = tid & 63;
    const int h = lane >> 3, k = lane & 7;
    for (int q = qq; q < P_; q += 4) {
        float Qv = S[q][h * 8 + k];
        float r[P_];
        float rsum = 0.f;
        #pragma unroll
        for (int p = 0; p < P_; ++p) {
            float prod = Qv * S[p][64 + h * 8 + k];
            prod += __shfl_xor(prod, 1, 64);
            prod += __shfl_xor(prod, 2, 64);
            prod += __shfl_xor(prod, 4, 64);
            float s = (prod / SQRT_DK) * Ds[h * 145 + q * 12 + p];
            r[p] = s; rsum += s;
        }
        float rs = fmaxf(fabsf(rsum), 1.0f);
        float acc = 0.f;
        #pragma unroll
        for (int p = 0; p < P_; ++p) acc += (r[p] / rs) * S[p][128 + h * 8 + k];
        att[((size_t)((b * P_ + q) * N_ + n)) * 64 + lane] = acc;
    }
}

// ---------- temporal enc-dec attention ----------
__global__ __launch_bounds__(256) void k_temporal(const float* __restrict__ qkv,
                                                  float* __restrict__ att) {
    const int bn = blockIdx.x;
    const int b = bn / N_, n = bn % N_;
    __shared__ float S[12][192];
    const int tid = threadIdx.x;
    for (int e = tid; e < 12 * 192; e += 256) {
        int p = e / 192, c = e % 192;
        S[p][c] = qkv[((size_t)((b * P_ + p) * N_ + n)) * 192 + c];
    }
    __syncthreads();
    const int qq = tid >> 6;
    const int lane = tid & 63;
    const int h = lane >> 3, k = lane & 7;
    for (int q = qq; q < P_; q += 4) {
        float Qv = S[q][h * 8 + k];
        float s[P_];
        float mx = -1e30f;
        #pragma unroll
        for (int p = 0; p < P_; ++p) {
            float prod = Qv * S[p][64 + h * 8 + k];
            prod += __shfl_xor(prod, 1, 64);
            prod += __shfl_xor(prod, 2, 64);
            prod += __shfl_xor(prod, 4, 64);
            float v = prod / SQRT_DK;
            s[p] = v; mx = fmaxf(mx, v);
        }
        float den = 0.f, acc = 0.f;
        #pragma unroll
        for (int p = 0; p < P_; ++p) {
            float e = expf(s[p] - mx);
            den += e;
            acc += e * S[p][128 + h * 8 + k];
        }
        att[((size_t)((b * P_ + q) * N_ + n)) * 64 + lane] = acc / den;
    }
}

// ---------- spatial attention v4: block (bp, h, g*4+ichunk); lanes span j ----------
__global__ __launch_bounds__(256) void k_spatial4(
    const float* __restrict__ qkvA, const float* __restrict__ qkvB,
    const float* __restrict__ Tm, const float* __restrict__ Am,
    float* __restrict__ attA, float* __restrict__ attB) {
    const int bp = blockIdx.x;          // 0..23
    const int h = blockIdx.y;           // 0..7
    const int g = blockIdx.z >> 2;      // 0,1
    const int ic = blockIdx.z & 3;      // i-chunk
    const float* qkv = g ? qkvB : qkvA;
    float* att = g ? attB : attA;

    __shared__ float sKt[8][192];       // [k][j] transposed
    __shared__ float sV[192][8];        // [j][k]
    __shared__ float sW[4][192];

    const int tid = threadIdx.x;
    for (int e = tid; e < 384; e += 256) {
        int j = e >> 1, kh = (e & 1) * 4;
        float4v k4 = {0.f, 0.f, 0.f, 0.f}, v4 = k4;
        if (j < N_) {
            const float* row = qkv + (size_t)(bp * N_ + j) * 192 + h * 8 + kh;
            k4 = *(const float4v*)(row + 64);
            v4 = *(const float4v*)(row + 128);
        }
        sKt[kh + 0][j] = k4.x;
        sKt[kh + 1][j] = k4.y;
        sKt[kh + 2][j] = k4.z;
        sKt[kh + 3][j] = k4.w;
        *(float4v*)&sV[j][kh] = v4;
    }
    __syncthreads();

    const int wv = tid >> 6;
    const int lane = tid & 63;
    const int j8 = lane >> 3, kk = lane & 7;

    const int i0 = ic * 43;
    const int i1 = (i0 + 43 < N_) ? (i0 + 43) : N_;

    for (int i = i0 + wv; i < i1; i += 4) {
        const float* qrow = qkv + (size_t)(bp * N_ + i) * 192 + h * 8;
        float4v qa = *(const float4v*)qrow;       // uniform: broadcast
        float4v qb = *(const float4v*)(qrow + 4);
        float Qi[8] = {qa.x, qa.y, qa.z, qa.w, qb.x, qb.y, qb.z, qb.w};
        const float* Trow = g ? (Am + (size_t)(bp * N_ + i) * N_) : (Tm + (size_t)i * N_);

        float sloc[3], tloc[3];
        float mx = -1e30f;
        #pragma unroll
        for (int c = 0; c < 3; ++c) {
            int j = c * 64 + lane;
            float tv = 0.f, s = -1e30f;
            if (j < N_) {
                tv = Trow[j];
                if (tv != 0.f) {
                    float dot = 0.f;
                    #pragma unroll
                    for (int k = 0; k < 8; ++k) dot += Qi[k] * sKt[k][j];
                    s = dot / SQRT_DK;
                } else {
                    s = 0.f;   // masked entries are exact zeros and DO enter the max
                }
            }
            sloc[c] = s; tloc[c] = tv;
            mx = fmaxf(mx, s);
        }
        #pragma unroll
        for (int off = 1; off < 64; off <<= 1) mx = fmaxf(mx, __shfl_xor(mx, off, 64));

        float den = 0.f;
        #pragma unroll
        for (int c = 0; c < 3; ++c) {
            float s = sloc[c];
            float e = (s != 0.f) ? expf(s - mx) : 0.f;  // j>=N_: s=-1e30 -> e==0
            den += e;
            sW[wv][c * 64 + lane] = e * tloc[c];
        }
        #pragma unroll
        for (int off = 1; off < 64; off <<= 1) den += __shfl_xor(den, off, 64);

        float acc = 0.f;
        #pragma unroll 4
        for (int j = j8; j < 192; j += 8) acc += sW[wv][j] * sV[j][kk];
        acc += __shfl_xor(acc, 8, 64);
        acc += __shfl_xor(acc, 16, 64);
        acc += __shfl_xor(acc, 32, 64);
        if (lane < 8)
            att[(size_t)(bp * N_ + i) * 64 + h * 8 + lane] = acc / (den + 1e-5f);
    }
}

// ---------- gdc over G=8,C=8 for one output dim (pointers may be LDS) ----------
__device__ __forceinline__ float gdc8(const float* dv, const float* W1,
                                      const float* W2, int dm) {
    float a[8], s[8];
    #pragma unroll
    for (int g = 0; g < 8; ++g) {
        float aa = 0.f, ss = 0.f;
        #pragma unroll
        for (int c = 0; c < 8; ++c) {
            float d = dv[g * 8 + c];
            aa += d * W1[(g * 8 + c) * 64 + dm];
            ss += d * W2[(g * 8 + c) * 64 + dm];
        }
        a[g] = aa; s[g] = fmaxf(ss, 0.f);
    }
    float mx = s[0];
    #pragma unroll
    for (int g = 1; g < 8; ++g) mx = fmaxf(mx, s[g]);
    float den = 0.f, o = 0.f;
    #pragma unroll
    for (int g = 0; g < 8; ++g) { float e = expf(s[g] - mx); den += e; o += a[g] * e; }
    return o / den;
}

__device__ __forceinline__ float ln_out(float r, int dm, const float* g, const float* b) {
    float m = r, m2 = r * r;
    #pragma unroll
    for (int off = 32; off; off >>= 1) { m += __shfl_xor(m, off, 64); m2 += __shfl_xor(m2, off, 64); }
    m *= (1.f / 64.f); m2 *= (1.f / 64.f);
    float var = m2 - m * m;
    return (r - m) * rsqrtf(var + 1e-5f) * g[dm] + b[dm];
}

// ---------- gsl v2: 8 tokens/block, weights LDS-staged once ----------
__global__ __launch_bounds__(256) void k_gsl2(const float* __restrict__ att,
    const float* __restrict__ xin,
    const float* __restrict__ W1, const float* __restrict__ W2,
    const float* __restrict__ wg, const float* __restrict__ bg,
    const float* __restrict__ wo, const float* __restrict__ bo,
    const float* __restrict__ lng, const float* __restrict__ lnb,
    float* __restrict__ xout) {
    __shared__ float W1s[4096], W2s[4096], wgs[4096], wos[4096];
    __shared__ float bgs[64], bos[64], lngs[64], lnbs[64];
    __shared__ float dv8[8][64], xv8[8][64], swv8[8][64];
    const int tid = threadIdx.x;
    const int t0 = blockIdx.x * 8;
    for (int e = tid; e < 1024; e += 256) {
        *(float4v*)&W1s[e * 4] = *(const float4v*)&W1[e * 4];
        *(float4v*)&W2s[e * 4] = *(const float4v*)&W2[e * 4];
        *(float4v*)&wgs[e * 4] = *(const float4v*)&wg[e * 4];
        *(float4v*)&wos[e * 4] = *(const float4v*)&wo[e * 4];
    }
    if (tid < 64) { bgs[tid] = bg[tid]; bos[tid] = bo[tid];
                    lngs[tid] = lng[tid]; lnbs[tid] = lnb[tid]; }
    for (int e = tid; e < 512; e += 256) {
        dv8[e >> 6][e & 63] = att[(size_t)(t0 + (e >> 6)) * 64 + (e & 63)];
        xv8[e >> 6][e & 63] = xin[(size_t)(t0 + (e >> 6)) * 64 + (e & 63)];
    }
    __syncthreads();
    const int wv = tid >> 6, dm = tid & 63;
    #pragma unroll
    for (int it = 0; it < 2; ++it) {
        const int tt = wv + it * 4;
        float o = gdc8(dv8[tt], W1s, W2s, dm);
        float hg = bgs[dm];
        #pragma unroll
        for (int d = 0; d < 64; ++d) hg += xv8[tt][d] * wgs[d * 64 + dm];
        hg *= o;
        swv8[tt][dm] = hg / (1.f + expf(-hg));   // wave-local slot: no barrier needed
        float ov = bos[dm];
        #pragma unroll
        for (int d = 0; d < 64; ++d) ov += swv8[tt][d] * wos[d * 64 + dm];
        float r = ov + xv8[tt][dm];
        xout[(size_t)(t0 + tt) * 64 + dm] = ln_out(r, dm, lngs, lnbs);
    }
}

// ---------- spatial tail v2: 16 tokens/block, two-phase LDS weight staging ----------
__global__ __launch_bounds__(256) void k_spatial_fuse2(
    const float* __restrict__ att0, const float* __restrict__ att1,
    const float* __restrict__ x1,
    const float* __restrict__ gs0_W1, const float* __restrict__ gs0_W2,
    const float* __restrict__ gs1_W1, const float* __restrict__ gs1_W2,
    const float* __restrict__ g2_W1, const float* __restrict__ g2_W2,
    const float* __restrict__ wg, const float* __restrict__ bg,
    const float* __restrict__ wo, const float* __restrict__ bo,
    const float* __restrict__ lng, const float* __restrict__ lnb,
    float* __restrict__ xout) {
    __shared__ float Wbuf[24576];                     // 96 KB, phased
    __shared__ float d0s[16][64], d1s[16][64], x1s[16][64];
    __shared__ float o0s[16][64], o1s[16][64], sws[16][64];
    __shared__ float bgs[64], bos[64], lngs[64], lnbs[64];
    const int tid = threadIdx.x;
    const int t0 = blockIdx.x * 16;
    // phase A: gdc weights
    for (int e = tid; e < 1024; e += 256) {
        *(float4v*)&Wbuf[e * 4]         = *(const float4v*)&gs0_W1[e * 4];
        *(float4v*)&Wbuf[4096 + e * 4]  = *(const float4v*)&gs0_W2[e * 4];
        *(float4v*)&Wbuf[8192 + e * 4]  = *(const float4v*)&gs1_W1[e * 4];
        *(float4v*)&Wbuf[12288 + e * 4] = *(const float4v*)&gs1_W2[e * 4];
    }
    if (tid < 64) { bgs[tid] = bg[tid]; bos[tid] = bo[tid];
                    lngs[tid] = lng[tid]; lnbs[tid] = lnb[tid]; }
    for (int e = tid; e < 1024; e += 256) {
        d0s[e >> 6][e & 63] = att0[(size_t)(t0 + (e >> 6)) * 64 + (e & 63)];
        d1s[e >> 6][e & 63] = att1[(size_t)(t0 + (e >> 6)) * 64 + (e & 63)];
        x1s[e >> 6][e & 63] = x1[(size_t)(t0 + (e >> 6)) * 64 + (e & 63)];
    }
    __syncthreads();
    const int wv = tid >> 6, dm = tid & 63;
    #pragma unroll
    for (int it = 0; it < 4; ++it) {
        const int tt = wv + it * 4;
        o0s[tt][dm] = gdc8(d0s[tt], Wbuf, Wbuf + 4096, dm);
        o1s[tt][dm] = gdc8(d1s[tt], Wbuf + 8192, Wbuf + 12288, dm);
    }
    __syncthreads();
    // phase B: g2 + swish weights overwrite Wbuf
    for (int e = tid; e < 2048; e += 256) {
        *(float4v*)&Wbuf[e * 4]        = *(const float4v*)&g2_W1[e * 4];
        *(float4v*)&Wbuf[8192 + e * 4] = *(const float4v*)&g2_W2[e * 4];
    }
    for (int e = tid; e < 1024; e += 256) {
        *(float4v*)&Wbuf[16384 + e * 4] = *(const float4v*)&wg[e * 4];
        *(float4v*)&Wbuf[20480 + e * 4] = *(const float4v*)&wo[e * 4];
    }
    __syncthreads();
    #pragma unroll
    for (int it = 0; it < 4; ++it) {
        const int tt = wv + it * 4;
        float a0 = 0.f, s0 = 0.f, a1 = 0.f, s1 = 0.f;
        #pragma unroll
        for (int c = 0; c < 64; ++c) {
            float v0 = o0s[tt][c], v1 = o1s[tt][c];
            a0 += v0 * Wbuf[c * 64 + dm];
            s0 += v0 * Wbuf[8192 + c * 64 + dm];
            a1 += v1 * Wbuf[4096 + c * 64 + dm];
            s1 += v1 * Wbuf[8192 + 4096 + c * 64 + dm];
        }
        s0 = fmaxf(s0, 0.f); s1 = fmaxf(s1, 0.f);
        float mx = fmaxf(s0, s1);
        float e0 = expf(s0 - mx), e1 = expf(s1 - mx);
        float o = (a0 * e0 + a1 * e1) / (e0 + e1);
        float hg = bgs[dm];
        #pragma unroll
        for (int d = 0; d < 64; ++d) hg += x1s[tt][d] * Wbuf[16384 + d * 64 + dm];
        hg *= o;
        sws[tt][dm] = hg / (1.f + expf(-hg));    // wave-local slot
        float ov = bos[dm];
        #pragma unroll
        for (int d = 0; d < 64; ++d) ov += sws[tt][d] * Wbuf[20480 + d * 64 + dm];
        float r = ov + x1s[tt][dm];
        xout[(size_t)(t0 + tt) * 64 + dm] = ln_out(r, dm, lngs, lnbs);
    }
}

// ---------- qkv projection v2: 8 tokens/block, LDS-staged weights ----------
__global__ __launch_bounds__(256) void k_qkvproj2(const float* __restrict__ x2,
    const float* __restrict__ enc,
    const float* __restrict__ wq, const float* __restrict__ wk,
    const float* __restrict__ wv,
    float* __restrict__ qkv) {
    __shared__ float wqs[4096], wks[4096], wvs[4096];
    __shared__ float xv8[8][64], ev8[8][64];
    const int tid = threadIdx.x;
    const int t0 = blockIdx.x * 8;
    for (int e = tid; e < 1024; e += 256) {
        *(float4v*)&wqs[e * 4] = *(const float4v*)&wq[e * 4];
        *(float4v*)&wks[e * 4] = *(const float4v*)&wk[e * 4];
        *(float4v*)&wvs[e * 4] = *(const float4v*)&wv[e * 4];
    }
    for (int e = tid; e < 512; e += 256) {
        xv8[e >> 6][e & 63] = x2[(size_t)(t0 + (e >> 6)) * 64 + (e & 63)];
        ev8[e >> 6][e & 63] = enc[(size_t)(t0 + (e >> 6)) * 64 + (e & 63)];
    }
    __syncthreads();
    const int wvx = tid >> 6, dm = tid & 63;
    #pragma unroll
    for (int it = 0; it < 2; ++it) {
        const int tt = wvx + it * 4;
        float aq = 0.f, ak = 0.f, av = 0.f;
        #pragma unroll
        for (int d = 0; d < 64; ++d) {
            aq += xv8[tt][d] * wqs[d * 64 + dm];
            ak += ev8[tt][d] * wks[d * 64 + dm];
            av += ev8[tt][d] * wvs[d * 64 + dm];
        }
        const size_t t = t0 + tt;
        qkv[t * 192 + dm] = aq;
        qkv[t * 192 + 64 + dm] = ak;
        qkv[t * 192 + 128 + dm] = av;
    }
}

// ---------- FFN v2: 8 tokens/block, two-phase LDS weight staging ----------
__global__ __launch_bounds__(256) void k_ffn2(const float* __restrict__ x3,
    const float* __restrict__ w1, const float* __restrict__ b1,
    const float* __restrict__ w2, const float* __restrict__ b2,
    const float* __restrict__ lng, const float* __restrict__ lnb,
    float* __restrict__ out) {
    __shared__ float Wbuf[16384];                 // 64 KB, phased (w1 then w2)
    __shared__ float hv8[8][256];
    __shared__ float xv8[8][64];
    __shared__ float b1s[256], b2s[64], lngs[64], lnbs[64];
    const int tid = threadIdx.x;
    const int t0 = blockIdx.x * 8;
    for (int e = tid; e < 4096; e += 256)
        *(float4v*)&Wbuf[e * 4] = *(const float4v*)&w1[e * 4];
    if (tid < 256) b1s[tid] = b1[tid];
    if (tid < 64) { b2s[tid] = b2[tid]; lngs[tid] = lng[tid]; lnbs[tid] = lnb[tid]; }
    for (int e = tid; e < 512; e += 256)
        xv8[e >> 6][e & 63] = x3[(size_t)(t0 + (e >> 6)) * 64 + (e & 63)];
    __syncthreads();
    const int wv = tid >> 6, dm = tid & 63;
    #pragma unroll
    for (int it = 0; it < 2; ++it) {
        const int tt = wv + it * 4;
        #pragma unroll
        for (int e = 0; e < 4; ++e) {
            int j = e * 64 + dm;
            float a = b1s[j];
            #pragma unroll
            for (int d = 0; d < 64; ++d) a += xv8[tt][d] * Wbuf[d * 256 + j];
            hv8[tt][j] = fmaxf(a, 0.f);
        }
    }
    __syncthreads();
    for (int e = tid; e < 4096; e += 256)
        *(float4v*)&Wbuf[e * 4] = *(const float4v*)&w2[e * 4];
    __syncthreads();
    #pragma unroll
    for (int it = 0; it < 2; ++it) {
        const int tt = wv + it * 4;
        float a = b2s[dm];
        for (int j = 0; j < 256; ++j) a += hv8[tt][j] * Wbuf[j * 64 + dm];
        float r = a + xv8[tt][dm];
        out[(size_t)(t0 + tt) * 64 + dm] = ln_out(r, dm, lngs, lnbs);
    }
}

} // namespace

extern "C" void kernel_launch(void* const* d_in, const int* in_sizes, int n_in,
                              void* d_out, int out_size, void* d_ws, size_t ws_size,
                              hipStream_t stream) {
    (void)in_sizes; (void)n_in; (void)out_size; (void)ws_size;
    const float* x    = (const float*)d_in[0];
    const float* c_x  = (const float*)d_in[1];
    const float* enc  = (const float*)d_in[2];
    const float* Tm   = (const float*)d_in[3];
    const float* Am   = (const float*)d_in[4];
    const float* Dm   = (const float*)d_in[5];
    const float* mr_w1 = (const float*)d_in[6];
    const float* mr_b1 = (const float*)d_in[7];
    const float* mr_w2 = (const float*)d_in[8];
    const float* mr_b2 = (const float*)d_in[9];
    const float* ms0_w1 = (const float*)d_in[10];
    const float* ms0_b1 = (const float*)d_in[11];
    const float* ms0_w2 = (const float*)d_in[12];
    const float* ms0_b2 = (const float*)d_in[13];
    const float* ms1_w1 = (const float*)d_in[14];
    const float* ms1_b1 = (const float*)d_in[15];
    const float* ms1_w2 = (const float*)d_in[16];
    const float* ms1_b2 = (const float*)d_in[17];
    const float* gr_W1 = (const float*)d_in[18];
    const float* gr_W2 = (const float*)d_in[19];
    const float* gs0_W1 = (const float*)d_in[20];
    const float* gs0_W2 = (const float*)d_in[21];
    const float* gs1_W1 = (const float*)d_in[22];
    const float* gs1_W2 = (const float*)d_in[23];
    const float* g2_W1 = (const float*)d_in[24];
    const float* g2_W2 = (const float*)d_in[25];
    const float* ge_W1 = (const float*)d_in[26];
    const float* ge_W2 = (const float*)d_in[27];
    const float* swr_wg = (const float*)d_in[28];
    const float* swr_bg = (const float*)d_in[29];
    const float* swr_wo = (const float*)d_in[30];
    const float* swr_bo = (const float*)d_in[31];
    const float* sws_wg = (const float*)d_in[32];
    const float* sws_bg = (const float*)d_in[33];
    const float* sws_wo = (const float*)d_in[34];
    const float* sws_bo = (const float*)d_in[35];
    const float* swe_wg = (const float*)d_in[36];
    const float* swe_bg = (const float*)d_in[37];
    const float* swe_wo = (const float*)d_in[38];
    const float* swe_bo = (const float*)d_in[39];
    const float* lnr_g = (const float*)d_in[40];
    const float* lnr_b = (const float*)d_in[41];
    const float* lns_g = (const float*)d_in[42];
    const float* lns_b = (const float*)d_in[43];
    const float* lne_g = (const float*)d_in[44];
    const float* lne_b = (const float*)d_in[45];
    const float* lnf_g = (const float*)d_in[46];
    const float* lnf_b = (const float*)d_in[47];
    const float* wq = (const float*)d_in[48];
    const float* wk = (const float*)d_in[49];
    const float* wv = (const float*)d_in[50];
    const float* f_w1 = (const float*)d_in[51];
    const float* f_b1 = (const float*)d_in[52];
    const float* f_w2 = (const float*)d_in[53];
    const float* f_b2 = (const float*)d_in[54];

    // workspace layout (~16.2 MB)
    float* ws   = (float*)d_ws;
    float* hr   = ws;                 // stage-2 graph0 hr
    float* hr2  = hr   + T_ * DH_;    // stage-2 graph1 hr
    float* qkva = hr2  + T_ * DH_;
    float* qkvb = qkva + T_ * 192;
    float* atta = qkvb + T_ * 192;
    float* attb = atta + T_ * DM_;    // also reused as stage-1 hr buffer
    float* x1f  = attb + T_ * DM_;
    float* x2f  = x1f  + T_ * DM_;
    float* x3f  = x2f  + T_ * DM_;
    unsigned short* Wfrag = (unsigned short*)(x3f + T_ * DM_);  // 3 graphs, 2.4 MB
    float* hr_r = attb;               // consumed before k_spatial4 writes attb

    // one-time permute of all three w2/b2 into bf16 B-fragment layout
    k_wconv<<<(3 * NG_ * NC_ * 64 + 255) / 256, 256, 0, stream>>>(
        mr_w2, mr_b2, ms0_w2, ms0_b2, ms1_w2, ms1_b2, Wfrag);

    // all three meta-hiddens depend only on c_x — one batched launch
    k_hr3<<<dim3(510, 3), 256, 0, stream>>>(c_x, mr_w1, mr_b1, ms0_w1, ms0_b1,
                                            ms1_w1, ms1_b1, hr_r, hr, hr2);

    // ---- stage 1: retnet retention ----
    k_meta_gemm2<<<dim3(64, 3, 1), 256, 0, stream>>>(
        hr_r, hr_r, x, Wfrag, Wfrag, qkva, qkva);
    k_retnet<<<B_ * N_, 256, 0, stream>>>(qkva, Dm, atta);
    k_gsl2<<<T_ / 8, 256, 0, stream>>>(atta, x, gr_W1, gr_W2, swr_wg, swr_bg,
                                       swr_wo, swr_bo, lnr_g, lnr_b, x1f);

    // ---- stage 2: spatial (predefined T + adaptive A) ----
    k_meta_gemm2<<<dim3(64, 3, 2), 256, 0, stream>>>(
        hr, hr2, x1f, Wfrag + WFRAG_G, Wfrag + 2 * WFRAG_G, qkva, qkvb);
    k_spatial4<<<dim3(B_ * P_, H_, 8), 256, 0, stream>>>(qkva, qkvb, Tm, Am, atta, attb);
    k_spatial_fuse2<<<T_ / 16, 256, 0, stream>>>(atta, attb, x1f,
                                                 gs0_W1, gs0_W2, gs1_W1, gs1_W2,
                                                 g2_W1, g2_W2, sws_wg, sws_bg,
                                                 sws_wo, sws_bo, lns_g, lns_b, x2f);

    // ---- stage 3: temporal encoder-decoder attention ----
    k_qkvproj2<<<T_ / 8, 256, 0, stream>>>(x2f, enc, wq, wk, wv, qkva);
    k_temporal<<<B_ * N_, 256, 0, stream>>>(qkva, atta);
    k_gsl2<<<T_ / 8, 256, 0, stream>>>(atta, x2f, ge_W1, ge_W2, swe_wg, swe_bg,
                                       swe_wo, swe_bo, lne_g, lne_b, x3f);

    // ---- stage 4: FFN ----
    k_ffn2<<<T_ / 8, 256, 0, stream>>>(x3f, f_w1, f_b1, f_w2, f_b2, lnf_g, lnf_b,
                                       (float*)d_out);
}

// Round 9
// 362.903 us; speedup vs baseline: 1.4269x; 1.4269x over previous
//
#include <hip/hip_runtime.h>
#include <hip/hip_bf16.h>
#include <math.h>

namespace {

constexpr int B_ = 2, P_ = 12, N_ = 170, DM_ = 64, H_ = 8, DK_ = 8, DH_ = 32, DF_ = 256;
constexpr int T_ = B_ * P_ * N_;        // 4080 tokens
constexpr float SQRT_DK = 2.8284271247461903f;

constexpr int NG_ = 12;                 // 192 output cols / 16
constexpr int NC_ = 66;                 // 2112 K / 32
constexpr int WFRAG_G = NG_ * NC_ * 64 * 8;   // shorts per graph = 405504

typedef __attribute__((ext_vector_type(4))) short short4v;
typedef __attribute__((ext_vector_type(8))) short short8v;
typedef __attribute__((ext_vector_type(4))) float float4v;

// float -> bf16 bits, round-to-nearest-even
__device__ __forceinline__ unsigned short f2bf(float x) {
    union { float f; unsigned int u; } c; c.f = x;
    unsigned int r = (c.u + 0x7FFFu + ((c.u >> 16) & 1u)) >> 16;
    return (unsigned short)r;
}

// ---------- meta hidden (x3 batched): hr = relu(c_x @ w1 + b1)  [T_,32] ----------
__global__ void k_hr3(const float* __restrict__ c_x,
                      const float* __restrict__ w1a, const float* __restrict__ b1a,
                      const float* __restrict__ w1b, const float* __restrict__ b1b,
                      const float* __restrict__ w1c, const float* __restrict__ b1c,
                      float* __restrict__ hra, float* __restrict__ hrb,
                      float* __restrict__ hrc) {
    int z = blockIdx.y;
    const float* w1 = z == 0 ? w1a : (z == 1 ? w1b : w1c);
    const float* b1 = z == 0 ? b1a : (z == 1 ? b1b : b1c);
    float* hr = z == 0 ? hra : (z == 1 ? hrb : hrc);
    int idx = blockIdx.x * 256 + threadIdx.x;          // t*32 + j
    if (idx >= T_ * DH_) return;
    int t = idx / DH_, j = idx % DH_;
    float acc = b1[j];
    const float* cx = c_x + t * DM_;
    #pragma unroll
    for (int d = 0; d < DM_; ++d) acc += cx[d] * w1[d * DH_ + j];
    hr[idx] = fmaxf(acc, 0.f);
}

// ---------- one-time w2/b2 -> bf16 B-fragment-linear permute ----------
__global__ void k_wconv(const float* __restrict__ w2a, const float* __restrict__ b2a,
                        const float* __restrict__ w2b, const float* __restrict__ b2b,
                        const float* __restrict__ w2c, const float* __restrict__ b2c,
                        unsigned short* __restrict__ Wfrag) {
    int idx = blockIdx.x * 256 + threadIdx.x;   // ((g*12+ng)*66+c)*64 + lane
    if (idx >= 3 * NG_ * NC_ * 64) return;
    int lane = idx & 63;
    int c = (idx >> 6) % NC_;
    int ng = (idx >> 6) / NC_ % NG_;
    int g = idx / (64 * NC_ * NG_);
    const float* w2 = g == 0 ? w2a : (g == 1 ? w2b : w2c);
    const float* b2 = g == 0 ? b2a : (g == 1 ? b2b : b2c);
    int m = ng * 16 + (lane & 15);
    int u = c >> 1;                              // jh
    int d0 = (c & 1) * 32 + (lane >> 4) * 8;
    const float* src = (u < DH_) ? (w2 + u * 12288 + m * 64 + d0) : (b2 + m * 64 + d0);
    short8v o;
    #pragma unroll
    for (int j = 0; j < 8; ++j) o[j] = (short)f2bf(src[j]);
    *(short8v*)(Wfrag + (size_t)idx * 8) = o;
}

// ---------- meta+mhlin GEMM v2: no LDS, no barriers ----------
__global__ __launch_bounds__(256) void k_meta_gemm2(
    const float* __restrict__ hr0, const float* __restrict__ hr1,
    const float* __restrict__ xin,
    const unsigned short* __restrict__ Wf0, const unsigned short* __restrict__ Wf1,
    float* __restrict__ out0, float* __restrict__ out1) {
    const int bz = blockIdx.z;
    const float* hr = bz ? hr1 : hr0;
    const unsigned short* Wf = bz ? Wf1 : Wf0;
    float* out = bz ? out1 : out0;

    const int tid = threadIdx.x;
    const int wv = tid >> 6, lane = tid & 63;
    const int l15 = lane & 15, quad = lane >> 4;
    const int g16 = blockIdx.x * 4 + wv;
    if (g16 >= 255) return;
    const int t = g16 * 16 + l15;
    const int nb = blockIdx.y;                   // 0..2

    const float* xp = xin + t * 64 + quad * 8;
    float4v xa = *(const float4v*)(xp);
    float4v xb = *(const float4v*)(xp + 4);
    float4v xc = *(const float4v*)(xp + 32);
    float4v xd = *(const float4v*)(xp + 36);
    float xr[16] = {xa.x, xa.y, xa.z, xa.w, xb.x, xb.y, xb.z, xb.w,
                    xc.x, xc.y, xc.z, xc.w, xd.x, xd.y, xd.z, xd.w};

    const float* hrp = hr + t * 32;
    float4v acc[4] = {{0.f,0.f,0.f,0.f},{0.f,0.f,0.f,0.f},
                      {0.f,0.f,0.f,0.f},{0.f,0.f,0.f,0.f}};

    const unsigned short* wb = Wf + ((size_t)(nb * 4) * NC_ * 64 + lane) * 8;
    const size_t qstride = (size_t)NC_ * 64 * 8;
    const size_t cstride = 64 * 8;

    for (int u = 0; u < 33; ++u) {
        float hrv = (u < DH_) ? hrp[u] : 1.0f;
        short8v a0, a1;
        #pragma unroll
        for (int j = 0; j < 8; ++j) {
            a0[j] = (short)f2bf(hrv * xr[j]);
            a1[j] = (short)f2bf(hrv * xr[8 + j]);
        }
        const unsigned short* wc = wb + (size_t)(2 * u) * cstride;
        #pragma unroll
        for (int q = 0; q < 4; ++q) {
            short8v b0 = *(const short8v*)(wc + q * qstride);
            short8v b1 = *(const short8v*)(wc + q * qstride + cstride);
            acc[q] = __builtin_amdgcn_mfma_f32_16x16x32_bf16(a0, b0, acc[q], 0, 0, 0);
            acc[q] = __builtin_amdgcn_mfma_f32_16x16x32_bf16(a1, b1, acc[q], 0, 0, 0);
        }
    }

    #pragma unroll
    for (int q = 0; q < 4; ++q) {
        #pragma unroll
        for (int r = 0; r < 4; ++r) {
            int tt = g16 * 16 + quad * 4 + r;
            out[tt * 192 + nb * 64 + q * 16 + l15] = acc[q][r];
        }
    }
}

// ---------- retnet temporal retention: block per (b,n), 256 thr ----------
__global__ __launch_bounds__(256) void k_retnet(const float* __restrict__ qkv,
                                                const float* __restrict__ Dm,
                                                float* __restrict__ att) {
    const int bn = blockIdx.x;           // b*N + n
    const int b = bn / N_, n = bn % N_;
    __shared__ float S[12][192];
    __shared__ float Ds[8 * 145];
    const int tid = threadIdx.x;
    for (int e = tid; e < 12 * 192; e += 256) {
        int p = e / 192, c = e % 192;
        S[p][c] = qkv[((size_t)((b * P_ + p) * N_ + n)) * 192 + c];
    }
    for (int e = tid; e < 1152; e += 256) {
        Ds[(e / 144) * 145 + (e % 144)] = Dm[e];
    }
    __syncthreads();
    const int qq = tid >> 6;
    const int lane = tid & 63;
    const int h = lane >> 3, k = lane & 7;
    for (int q = qq; q < P_; q += 4) {
        float Qv = S[q][h * 8 + k];
        float r[P_];
        float rsum = 0.f;
        #pragma unroll
        for (int p = 0; p < P_; ++p) {
            float prod = Qv * S[p][64 + h * 8 + k];
            prod += __shfl_xor(prod, 1, 64);
            prod += __shfl_xor(prod, 2, 64);
            prod += __shfl_xor(prod, 4, 64);
            float s = (prod / SQRT_DK) * Ds[h * 145 + q * 12 + p];
            r[p] = s; rsum += s;
        }
        float rs = fmaxf(fabsf(rsum), 1.0f);
        float acc = 0.f;
        #pragma unroll
        for (int p = 0; p < P_; ++p) acc += (r[p] / rs) * S[p][128 + h * 8 + k];
        att[((size_t)((b * P_ + q) * N_ + n)) * 64 + lane] = acc;
    }
}

// ---------- temporal enc-dec attention ----------
__global__ __launch_bounds__(256) void k_temporal(const float* __restrict__ qkv,
                                                  float* __restrict__ att) {
    const int bn = blockIdx.x;
    const int b = bn / N_, n = bn % N_;
    __shared__ float S[12][192];
    const int tid = threadIdx.x;
    for (int e = tid; e < 12 * 192; e += 256) {
        int p = e / 192, c = e % 192;
        S[p][c] = qkv[((size_t)((b * P_ + p) * N_ + n)) * 192 + c];
    }
    __syncthreads();
    const int qq = tid >> 6;
    const int lane = tid & 63;
    const int h = lane >> 3, k = lane & 7;
    for (int q = qq; q < P_; q += 4) {
        float Qv = S[q][h * 8 + k];
        float s[P_];
        float mx = -1e30f;
        #pragma unroll
        for (int p = 0; p < P_; ++p) {
            float prod = Qv * S[p][64 + h * 8 + k];
            prod += __shfl_xor(prod, 1, 64);
            prod += __shfl_xor(prod, 2, 64);
            prod += __shfl_xor(prod, 4, 64);
            float v = prod / SQRT_DK;
            s[p] = v; mx = fmaxf(mx, v);
        }
        float den = 0.f, acc = 0.f;
        #pragma unroll
        for (int p = 0; p < P_; ++p) {
            float e = expf(s[p] - mx);
            den += e;
            acc += e * S[p][128 + h * 8 + k];
        }
        att[((size_t)((b * P_ + q) * N_ + n)) * 64 + lane] = acc / den;
    }
}

// ---------- spatial attention v4: block (bp, h, g*4+ichunk); lanes span j ----------
__global__ __launch_bounds__(256) void k_spatial4(
    const float* __restrict__ qkvA, const float* __restrict__ qkvB,
    const float* __restrict__ Tm, const float* __restrict__ Am,
    float* __restrict__ attA, float* __restrict__ attB) {
    const int bp = blockIdx.x;          // 0..23
    const int h = blockIdx.y;           // 0..7
    const int g = blockIdx.z >> 2;      // 0,1
    const int ic = blockIdx.z & 3;      // i-chunk
    const float* qkv = g ? qkvB : qkvA;
    float* att = g ? attB : attA;

    __shared__ float sKt[8][192];       // [k][j] transposed
    __shared__ float sV[192][8];        // [j][k]
    __shared__ float sW[4][192];

    const int tid = threadIdx.x;
    for (int e = tid; e < 384; e += 256) {
        int j = e >> 1, kh = (e & 1) * 4;
        float4v k4 = {0.f, 0.f, 0.f, 0.f}, v4 = k4;
        if (j < N_) {
            const float* row = qkv + (size_t)(bp * N_ + j) * 192 + h * 8 + kh;
            k4 = *(const float4v*)(row + 64);
            v4 = *(const float4v*)(row + 128);
        }
        sKt[kh + 0][j] = k4.x;
        sKt[kh + 1][j] = k4.y;
        sKt[kh + 2][j] = k4.z;
        sKt[kh + 3][j] = k4.w;
        *(float4v*)&sV[j][kh] = v4;
    }
    __syncthreads();

    const int wv = tid >> 6;
    const int lane = tid & 63;
    const int j8 = lane >> 3, kk = lane & 7;

    const int i0 = ic * 43;
    const int i1 = (i0 + 43 < N_) ? (i0 + 43) : N_;

    for (int i = i0 + wv; i < i1; i += 4) {
        const float* qrow = qkv + (size_t)(bp * N_ + i) * 192 + h * 8;
        float4v qa = *(const float4v*)qrow;       // uniform: broadcast
        float4v qb = *(const float4v*)(qrow + 4);
        float Qi[8] = {qa.x, qa.y, qa.z, qa.w, qb.x, qb.y, qb.z, qb.w};
        const float* Trow = g ? (Am + (size_t)(bp * N_ + i) * N_) : (Tm + (size_t)i * N_);

        float sloc[3], tloc[3];
        float mx = -1e30f;
        #pragma unroll
        for (int c = 0; c < 3; ++c) {
            int j = c * 64 + lane;
            float tv = 0.f, s = -1e30f;
            if (j < N_) {
                tv = Trow[j];
                if (tv != 0.f) {
                    float dot = 0.f;
                    #pragma unroll
                    for (int k = 0; k < 8; ++k) dot += Qi[k] * sKt[k][j];
                    s = dot / SQRT_DK;
                } else {
                    s = 0.f;   // masked entries are exact zeros and DO enter the max
                }
            }
            sloc[c] = s; tloc[c] = tv;
            mx = fmaxf(mx, s);
        }
        #pragma unroll
        for (int off = 1; off < 64; off <<= 1) mx = fmaxf(mx, __shfl_xor(mx, off, 64));

        float den = 0.f;
        #pragma unroll
        for (int c = 0; c < 3; ++c) {
            float s = sloc[c];
            float e = (s != 0.f) ? expf(s - mx) : 0.f;  // j>=N_: s=-1e30 -> e==0
            den += e;
            sW[wv][c * 64 + lane] = e * tloc[c];
        }
        #pragma unroll
        for (int off = 1; off < 64; off <<= 1) den += __shfl_xor(den, off, 64);

        float acc = 0.f;
        #pragma unroll 4
        for (int j = j8; j < 192; j += 8) acc += sW[wv][j] * sV[j][kk];
        acc += __shfl_xor(acc, 8, 64);
        acc += __shfl_xor(acc, 16, 64);
        acc += __shfl_xor(acc, 32, 64);
        if (lane < 8)
            att[(size_t)(bp * N_ + i) * 64 + h * 8 + lane] = acc / (den + 1e-5f);
    }
}

__device__ __forceinline__ float ln_out(float r, int dm, const float* g, const float* b) {
    float m = r, m2 = r * r;
    #pragma unroll
    for (int off = 32; off; off >>= 1) { m += __shfl_xor(m, off, 64); m2 += __shfl_xor(m2, off, 64); }
    m *= (1.f / 64.f); m2 *= (1.f / 64.f);
    float var = m2 - m * m;
    return (r - m) * rsqrtf(var + 1e-5f) * g[dm] + b[dm];
}

// ---------- gsl v3: 8 tokens/block (2/wave), weights reused in registers ----------
__global__ __launch_bounds__(256) void k_gsl3(const float* __restrict__ att,
    const float* __restrict__ xin,
    const float* __restrict__ W1, const float* __restrict__ W2,
    const float* __restrict__ wg, const float* __restrict__ bg,
    const float* __restrict__ wo, const float* __restrict__ bo,
    const float* __restrict__ lng, const float* __restrict__ lnb,
    float* __restrict__ xout) {
    __shared__ float dv[8][64], xv[8][64], sw[8][64];
    const int tid = threadIdx.x;
    const int t0 = blockIdx.x * 8;
    for (int e = tid; e < 512; e += 256) {
        dv[e >> 6][e & 63] = att[(size_t)(t0 + (e >> 6)) * 64 + (e & 63)];
        xv[e >> 6][e & 63] = xin[(size_t)(t0 + (e >> 6)) * 64 + (e & 63)];
    }
    __syncthreads();
    const int wv = tid >> 6, dm = tid & 63;
    const int r0 = wv * 2, r1 = r0 + 1;
    // gdc for both tokens: weight loaded once, used twice
    float a[2][8], s[2][8];
    #pragma unroll
    for (int g = 0; g < 8; ++g)
        #pragma unroll
        for (int tt = 0; tt < 2; ++tt) { a[tt][g] = 0.f; s[tt][g] = 0.f; }
    for (int g = 0; g < 8; ++g) {
        #pragma unroll
        for (int c = 0; c < 8; ++c) {
            int idx = (g * 8 + c) * 64 + dm;
            float w1v = W1[idx], w2v = W2[idx];
            float d0 = dv[r0][g * 8 + c], d1 = dv[r1][g * 8 + c];
            a[0][g] += d0 * w1v; s[0][g] += d0 * w2v;
            a[1][g] += d1 * w1v; s[1][g] += d1 * w2v;
        }
    }
    float o[2];
    #pragma unroll
    for (int tt = 0; tt < 2; ++tt) {
        float mx = fmaxf(s[tt][0], 0.f);
        #pragma unroll
        for (int g = 1; g < 8; ++g) mx = fmaxf(mx, fmaxf(s[tt][g], 0.f));
        float den = 0.f, oo = 0.f;
        #pragma unroll
        for (int g = 0; g < 8; ++g) {
            float e = expf(fmaxf(s[tt][g], 0.f) - mx);
            den += e; oo += a[tt][g] * e;
        }
        o[tt] = oo / den;
    }
    float hg0 = bg[dm], hg1 = hg0;
    for (int d = 0; d < 64; ++d) {
        float w = wg[d * 64 + dm];
        hg0 += xv[r0][d] * w;
        hg1 += xv[r1][d] * w;
    }
    hg0 *= o[0]; hg1 *= o[1];
    sw[r0][dm] = hg0 / (1.f + expf(-hg0));   // wave-local rows: no barrier
    sw[r1][dm] = hg1 / (1.f + expf(-hg1));
    float ov0 = bo[dm], ov1 = ov0;
    for (int d = 0; d < 64; ++d) {
        float w = wo[d * 64 + dm];
        ov0 += sw[r0][d] * w;
        ov1 += sw[r1][d] * w;
    }
    float rr0 = ov0 + xv[r0][dm];
    float rr1 = ov1 + xv[r1][dm];
    xout[(size_t)(t0 + r0) * 64 + dm] = ln_out(rr0, dm, lng, lnb);
    xout[(size_t)(t0 + r1) * 64 + dm] = ln_out(rr1, dm, lng, lnb);
}

// ---------- spatial tail v3: 8 tokens/block (2/wave), register weight reuse ----------
__global__ __launch_bounds__(256) void k_spatial_fuse3(
    const float* __restrict__ att0, const float* __restrict__ att1,
    const float* __restrict__ x1,
    const float* __restrict__ gs0_W1, const float* __restrict__ gs0_W2,
    const float* __restrict__ gs1_W1, const float* __restrict__ gs1_W2,
    const float* __restrict__ g2_W1, const float* __restrict__ g2_W2,
    const float* __restrict__ wg, const float* __restrict__ bg,
    const float* __restrict__ wo, const float* __restrict__ bo,
    const float* __restrict__ lng, const float* __restrict__ lnb,
    float* __restrict__ xout) {
    __shared__ float d0s[8][64], d1s[8][64], x1s[8][64];
    __shared__ float o0s[8][64], o1s[8][64], sws[8][64];
    const int tid = threadIdx.x;
    const int t0 = blockIdx.x * 8;
    for (int e = tid; e < 512; e += 256) {
        d0s[e >> 6][e & 63] = att0[(size_t)(t0 + (e >> 6)) * 64 + (e & 63)];
        d1s[e >> 6][e & 63] = att1[(size_t)(t0 + (e >> 6)) * 64 + (e & 63)];
        x1s[e >> 6][e & 63] = x1[(size_t)(t0 + (e >> 6)) * 64 + (e & 63)];
    }
    __syncthreads();
    const int wv = tid >> 6, dm = tid & 63;
    const int r0 = wv * 2, r1 = r0 + 1;
    // gdc graph0 then graph1 (wave-local o rows)
    #pragma unroll
    for (int gr = 0; gr < 2; ++gr) {
        const float* W1 = gr ? gs1_W1 : gs0_W1;
        const float* W2 = gr ? gs1_W2 : gs0_W2;
        const float (*ds)[64] = gr ? d1s : d0s;
        float (*os)[64] = gr ? o1s : o0s;
        float a[2][8], s[2][8];
        #pragma unroll
        for (int g = 0; g < 8; ++g)
            #pragma unroll
            for (int tt = 0; tt < 2; ++tt) { a[tt][g] = 0.f; s[tt][g] = 0.f; }
        for (int g = 0; g < 8; ++g) {
            #pragma unroll
            for (int c = 0; c < 8; ++c) {
                int idx = (g * 8 + c) * 64 + dm;
                float w1v = W1[idx], w2v = W2[idx];
                float dd0 = ds[r0][g * 8 + c], dd1 = ds[r1][g * 8 + c];
                a[0][g] += dd0 * w1v; s[0][g] += dd0 * w2v;
                a[1][g] += dd1 * w1v; s[1][g] += dd1 * w2v;
            }
        }
        #pragma unroll
        for (int tt = 0; tt < 2; ++tt) {
            float mx = fmaxf(s[tt][0], 0.f);
            #pragma unroll
            for (int g = 1; g < 8; ++g) mx = fmaxf(mx, fmaxf(s[tt][g], 0.f));
            float den = 0.f, oo = 0.f;
            #pragma unroll
            for (int g = 0; g < 8; ++g) {
                float e = expf(fmaxf(s[tt][g], 0.f) - mx);
                den += e; oo += a[tt][g] * e;
            }
            os[wv * 2 + tt][dm] = oo / den;      // wave-local write
        }
    }
    // g2 combine (G=2, C=64), weights loaded once per (c), used for 2 tokens
    float a0[2] = {0.f, 0.f}, s0[2] = {0.f, 0.f}, a1[2] = {0.f, 0.f}, s1[2] = {0.f, 0.f};
    for (int c = 0; c < 64; ++c) {
        float wa0 = g2_W1[c * 64 + dm];
        float ws0 = g2_W2[c * 64 + dm];
        float wa1 = g2_W1[(64 + c) * 64 + dm];
        float ws1 = g2_W2[(64 + c) * 64 + dm];
        #pragma unroll
        for (int tt = 0; tt < 2; ++tt) {
            float v0 = o0s[wv * 2 + tt][c], v1 = o1s[wv * 2 + tt][c];
            a0[tt] += v0 * wa0; s0[tt] += v0 * ws0;
            a1[tt] += v1 * wa1; s1[tt] += v1 * ws1;
        }
    }
    float o[2];
    #pragma unroll
    for (int tt = 0; tt < 2; ++tt) {
        float ss0 = fmaxf(s0[tt], 0.f), ss1 = fmaxf(s1[tt], 0.f);
        float mx = fmaxf(ss0, ss1);
        float e0 = expf(ss0 - mx), e1 = expf(ss1 - mx);
        o[tt] = (a0[tt] * e0 + a1[tt] * e1) / (e0 + e1);
    }
    float hg0 = bg[dm], hg1 = hg0;
    for (int d = 0; d < 64; ++d) {
        float w = wg[d * 64 + dm];
        hg0 += x1s[r0][d] * w;
        hg1 += x1s[r1][d] * w;
    }
    hg0 *= o[0]; hg1 *= o[1];
    sws[r0][dm] = hg0 / (1.f + expf(-hg0));
    sws[r1][dm] = hg1 / (1.f + expf(-hg1));
    float ov0 = bo[dm], ov1 = ov0;
    for (int d = 0; d < 64; ++d) {
        float w = wo[d * 64 + dm];
        ov0 += sws[r0][d] * w;
        ov1 += sws[r1][d] * w;
    }
    float rr0 = ov0 + x1s[r0][dm];
    float rr1 = ov1 + x1s[r1][dm];
    xout[(size_t)(t0 + r0) * 64 + dm] = ln_out(rr0, dm, lng, lnb);
    xout[(size_t)(t0 + r1) * 64 + dm] = ln_out(rr1, dm, lng, lnb);
}

// ---------- qkv projection v3: 8 tokens/block (2/wave) ----------
__global__ __launch_bounds__(256) void k_qkvproj3(const float* __restrict__ x2,
    const float* __restrict__ enc,
    const float* __restrict__ wq, const float* __restrict__ wk,
    const float* __restrict__ wvp,
    float* __restrict__ qkv) {
    __shared__ float xs[8][64], es[8][64];
    const int tid = threadIdx.x;
    const int t0 = blockIdx.x * 8;
    for (int e = tid; e < 512; e += 256) {
        xs[e >> 6][e & 63] = x2[(size_t)(t0 + (e >> 6)) * 64 + (e & 63)];
        es[e >> 6][e & 63] = enc[(size_t)(t0 + (e >> 6)) * 64 + (e & 63)];
    }
    __syncthreads();
    const int wv = tid >> 6, dm = tid & 63;
    const int r0 = wv * 2, r1 = r0 + 1;
    float aq0 = 0.f, ak0 = 0.f, av0 = 0.f, aq1 = 0.f, ak1 = 0.f, av1 = 0.f;
    for (int d = 0; d < 64; ++d) {
        float q = wq[d * 64 + dm], k = wk[d * 64 + dm], v = wvp[d * 64 + dm];
        float x0 = xs[r0][d], x1v = xs[r1][d];
        float e0 = es[r0][d], e1 = es[r1][d];
        aq0 += x0 * q; ak0 += e0 * k; av0 += e0 * v;
        aq1 += x1v * q; ak1 += e1 * k; av1 += e1 * v;
    }
    size_t tg0 = t0 + r0, tg1 = t0 + r1;
    qkv[tg0 * 192 + dm] = aq0;       qkv[tg1 * 192 + dm] = aq1;
    qkv[tg0 * 192 + 64 + dm] = ak0;  qkv[tg1 * 192 + 64 + dm] = ak1;
    qkv[tg0 * 192 + 128 + dm] = av0; qkv[tg1 * 192 + 128 + dm] = av1;
}

// ---------- FFN v3: 8 tokens/block (2/wave), hv in LDS (wave-local) ----------
__global__ __launch_bounds__(256) void k_ffn3(const float* __restrict__ x3,
    const float* __restrict__ w1, const float* __restrict__ b1,
    const float* __restrict__ w2, const float* __restrict__ b2,
    const float* __restrict__ lng, const float* __restrict__ lnb,
    float* __restrict__ out) {
    __shared__ float xs[8][64];
    __shared__ float hv[8][256];
    const int tid = threadIdx.x;
    const int t0 = blockIdx.x * 8;
    for (int e = tid; e < 512; e += 256)
        xs[e >> 6][e & 63] = x3[(size_t)(t0 + (e >> 6)) * 64 + (e & 63)];
    __syncthreads();
    const int wv = tid >> 6, dm = tid & 63;
    const int r0 = wv * 2, r1 = r0 + 1;
    #pragma unroll
    for (int e = 0; e < 4; ++e) {
        int j = e * 64 + dm;
        float b = b1[j];
        float a0 = b, a1 = b;
        for (int d = 0; d < 64; ++d) {
            float w = w1[d * 256 + j];
            a0 += xs[r0][d] * w;
            a1 += xs[r1][d] * w;
        }
        hv[r0][j] = fmaxf(a0, 0.f);    // wave-local rows
        hv[r1][j] = fmaxf(a1, 0.f);
    }
    float b = b2[dm];
    float a0 = b, a1 = b;
    for (int j = 0; j < 256; ++j) {
        float w = w2[j * 64 + dm];
        a0 += hv[r0][j] * w;
        a1 += hv[r1][j] * w;
    }
    float rr0 = a0 + xs[r0][dm];
    float rr1 = a1 + xs[r1][dm];
    out[(size_t)(t0 + r0) * 64 + dm] = ln_out(rr0, dm, lng, lnb);
    out[(size_t)(t0 + r1) * 64 + dm] = ln_out(rr1, dm, lng, lnb);
}

} // namespace

extern "C" void kernel_launch(void* const* d_in, const int* in_sizes, int n_in,
                              void* d_out, int out_size, void* d_ws, size_t ws_size,
                              hipStream_t stream) {
    (void)in_sizes; (void)n_in; (void)out_size; (void)ws_size;
    const float* x    = (const float*)d_in[0];
    const float* c_x  = (const float*)d_in[1];
    const float* enc  = (const float*)d_in[2];
    const float* Tm   = (const float*)d_in[3];
    const float* Am   = (const float*)d_in[4];
    const float* Dm   = (const float*)d_in[5];
    const float* mr_w1 = (const float*)d_in[6];
    const float* mr_b1 = (const float*)d_in[7];
    const float* mr_w2 = (const float*)d_in[8];
    const float* mr_b2 = (const float*)d_in[9];
    const float* ms0_w1 = (const float*)d_in[10];
    const float* ms0_b1 = (const float*)d_in[11];
    const float* ms0_w2 = (const float*)d_in[12];
    const float* ms0_b2 = (const float*)d_in[13];
    const float* ms1_w1 = (const float*)d_in[14];
    const float* ms1_b1 = (const float*)d_in[15];
    const float* ms1_w2 = (const float*)d_in[16];
    const float* ms1_b2 = (const float*)d_in[17];
    const float* gr_W1 = (const float*)d_in[18];
    const float* gr_W2 = (const float*)d_in[19];
    const float* gs0_W1 = (const float*)d_in[20];
    const float* gs0_W2 = (const float*)d_in[21];
    const float* gs1_W1 = (const float*)d_in[22];
    const float* gs1_W2 = (const float*)d_in[23];
    const float* g2_W1 = (const float*)d_in[24];
    const float* g2_W2 = (const float*)d_in[25];
    const float* ge_W1 = (const float*)d_in[26];
    const float* ge_W2 = (const float*)d_in[27];
    const float* swr_wg = (const float*)d_in[28];
    const float* swr_bg = (const float*)d_in[29];
    const float* swr_wo = (const float*)d_in[30];
    const float* swr_bo = (const float*)d_in[31];
    const float* sws_wg = (const float*)d_in[32];
    const float* sws_bg = (const float*)d_in[33];
    const float* sws_wo = (const float*)d_in[34];
    const float* sws_bo = (const float*)d_in[35];
    const float* swe_wg = (const float*)d_in[36];
    const float* swe_bg = (const float*)d_in[37];
    const float* swe_wo = (const float*)d_in[38];
    const float* swe_bo = (const float*)d_in[39];
    const float* lnr_g = (const float*)d_in[40];
    const float* lnr_b = (const float*)d_in[41];
    const float* lns_g = (const float*)d_in[42];
    const float* lns_b = (const float*)d_in[43];
    const float* lne_g = (const float*)d_in[44];
    const float* lne_b = (const float*)d_in[45];
    const float* lnf_g = (const float*)d_in[46];
    const float* lnf_b = (const float*)d_in[47];
    const float* wq = (const float*)d_in[48];
    const float* wk = (const float*)d_in[49];
    const float* wv = (const float*)d_in[50];
    const float* f_w1 = (const float*)d_in[51];
    const float* f_b1 = (const float*)d_in[52];
    const float* f_w2 = (const float*)d_in[53];
    const float* f_b2 = (const float*)d_in[54];

    // workspace layout (~16.2 MB)
    float* ws   = (float*)d_ws;
    float* hr   = ws;                 // stage-2 graph0 hr
    float* hr2  = hr   + T_ * DH_;    // stage-2 graph1 hr
    float* qkva = hr2  + T_ * DH_;
    float* qkvb = qkva + T_ * 192;
    float* atta = qkvb + T_ * 192;
    float* attb = atta + T_ * DM_;    // also reused as stage-1 hr buffer
    float* x1f  = attb + T_ * DM_;
    float* x2f  = x1f  + T_ * DM_;
    float* x3f  = x2f  + T_ * DM_;
    unsigned short* Wfrag = (unsigned short*)(x3f + T_ * DM_);  // 3 graphs, 2.4 MB
    float* hr_r = attb;               // consumed before k_spatial4 writes attb

    // one-time permute of all three w2/b2 into bf16 B-fragment layout
    k_wconv<<<(3 * NG_ * NC_ * 64 + 255) / 256, 256, 0, stream>>>(
        mr_w2, mr_b2, ms0_w2, ms0_b2, ms1_w2, ms1_b2, Wfrag);

    // all three meta-hiddens depend only on c_x — one batched launch
    k_hr3<<<dim3(510, 3), 256, 0, stream>>>(c_x, mr_w1, mr_b1, ms0_w1, ms0_b1,
                                            ms1_w1, ms1_b1, hr_r, hr, hr2);

    // ---- stage 1: retnet retention ----
    k_meta_gemm2<<<dim3(64, 3, 1), 256, 0, stream>>>(
        hr_r, hr_r, x, Wfrag, Wfrag, qkva, qkva);
    k_retnet<<<B_ * N_, 256, 0, stream>>>(qkva, Dm, atta);
    k_gsl3<<<T_ / 8, 256, 0, stream>>>(atta, x, gr_W1, gr_W2, swr_wg, swr_bg,
                                       swr_wo, swr_bo, lnr_g, lnr_b, x1f);

    // ---- stage 2: spatial (predefined T + adaptive A) ----
    k_meta_gemm2<<<dim3(64, 3, 2), 256, 0, stream>>>(
        hr, hr2, x1f, Wfrag + WFRAG_G, Wfrag + 2 * WFRAG_G, qkva, qkvb);
    k_spatial4<<<dim3(B_ * P_, H_, 8), 256, 0, stream>>>(qkva, qkvb, Tm, Am, atta, attb);
    k_spatial_fuse3<<<T_ / 8, 256, 0, stream>>>(atta, attb, x1f,
                                                gs0_W1, gs0_W2, gs1_W1, gs1_W2,
                                                g2_W1, g2_W2, sws_wg, sws_bg,
                                                sws_wo, sws_bo, lns_g, lns_b, x2f);

    // ---- stage 3: temporal encoder-decoder attention ----
    k_qkvproj3<<<T_ / 8, 256, 0, stream>>>(x2f, enc, wq, wk, wv, qkva);
    k_temporal<<<B_ * N_, 256, 0, stream>>>(qkva, atta);
    k_gsl3<<<T_ / 8, 256, 0, stream>>>(atta, x2f, ge_W1, ge_W2, swe_wg, swe_bg,
                                       swe_wo, swe_bo, lne_g, lne_b, x3f);

    // ---- stage 4: FFN ----
    k_ffn3<<<T_ / 8, 256, 0, stream>>>(x3f, f_w1, f_b1, f_w2, f_b2, lnf_g, lnf_b,
                                       (float*)d_out);
}